// Round 7
// baseline (321.204 us; speedup 1.0000x reference)
//
#include <hip/hip_runtime.h>
#include <stdint.h>

// PinConv pipeline: bf16-MFMA GEMMs (fused colstats, STRIPED fp64 atomics) +
// locality-binned CSR gather. Round 7: stats accumulators striped 32-way
// (slot = blockIdx & 31) to kill same-address fp64 atomic serialization that
// made gemm_bn 45us (782-way contention -> 25-way). Consumers reduce slots.

#define BN_EPS 1e-5f
#define NSLOT 32

typedef __attribute__((ext_vector_type(8))) short bf16x8;
typedef __attribute__((ext_vector_type(4))) float f32x4;

static __device__ __forceinline__ unsigned short f2bf(float f) {
    uint32_t u = __builtin_bit_cast(uint32_t, f);
    u += 0x7fffu + ((u >> 16) & 1u);          // round-to-nearest-even
    return (unsigned short)(u >> 16);
}
static __device__ __forceinline__ float bf_lo(uint32_t u) {
    return __builtin_bit_cast(float, u << 16);
}
static __device__ __forceinline__ float bf_hi(uint32_t u) {
    return __builtin_bit_cast(float, u & 0xffff0000u);
}

// ---------------------------------------------------------------------------
// Fused: blocks [0,CB) cast feat f32->bf16; blocks [CB,..) histogram dst.
__global__ __launch_bounds__(256) void k_pre(
    const float* __restrict__ feat, unsigned short* __restrict__ featb, int nf,
    const int* __restrict__ dst, int* __restrict__ cnt, int E, int CB)
{
    if ((int)blockIdx.x < CB) {
        int i = (blockIdx.x * 256 + threadIdx.x) * 4;
        if (i + 3 < nf) {
            float4 v = *(const float4*)(feat + i);
            ushort4 o;
            o.x = f2bf(v.x); o.y = f2bf(v.y); o.z = f2bf(v.z); o.w = f2bf(v.w);
            *(ushort4*)(featb + i) = o;
        } else {
            for (int j = i; j < nf; ++j) featb[j] = f2bf(feat[j]);
        }
    } else {
        int e = (blockIdx.x - CB) * 256 + threadIdx.x;
        if (e < E) atomicAdd(&cnt[dst[e]], 1);
    }
}

// ---------------------------------------------------------------------------
// Scan phase 1: each block scans 4096 elems (1024 thr x int4), cnt zero-padded.
__global__ __launch_bounds__(1024) void k_scan_part(
    const int* __restrict__ cnt, int* __restrict__ offs,
    int* __restrict__ bsum)
{
    __shared__ int wsum[16];
    const int tid = threadIdx.x, lane = tid & 63, wv = tid >> 6;
    const int i = blockIdx.x * 4096 + tid * 4;
    int4 v = *(const int4*)(cnt + i);
    int s = v.x + v.y + v.z + v.w;
    int incl = s;
#pragma unroll
    for (int o = 1; o < 64; o <<= 1) {
        int t = __shfl_up(incl, o, 64);
        if (lane >= o) incl += t;
    }
    if (lane == 63) wsum[wv] = incl;
    __syncthreads();
    if (wv == 0 && lane < 16) {
        int t = wsum[lane];
        int ss = t;
#pragma unroll
        for (int o = 1; o < 16; o <<= 1) {
            int u = __shfl_up(ss, o, 64);
            if (lane >= o) ss += u;
        }
        wsum[lane] = ss - t;
        if (lane == 15 && bsum) bsum[blockIdx.x] = ss;
    }
    __syncthreads();
    int e0 = wsum[wv] + incl - s;
    int4 o;
    o.x = e0; o.y = e0 + v.x; o.z = o.y + v.y; o.w = o.z + v.z;
    *(int4*)(offs + i) = o;
}

// Scan phase 2: add block prefix, emit gcur bucket cursors, offs[N]=E.
__global__ __launch_bounds__(1024) void k_scan_fix(
    int* __restrict__ offs, const int* __restrict__ bsum,
    int* __restrict__ gcur, int N, int E)
{
    __shared__ int pre_s;
    const int tid = threadIdx.x;
    if (tid == 0) {
        int p = 0;
        for (int j = 0; j < (int)blockIdx.x; ++j) p += bsum[j];
        pre_s = p;
    }
    __syncthreads();
    const int pre = pre_s;
    const int i = blockIdx.x * 4096 + tid * 4;
    int4 v = *(const int4*)(offs + i);
    v.x += pre; v.y += pre; v.z += pre; v.w += pre;
    if (i + 3 < N) {
        *(int4*)(offs + i) = v;
    } else {
        int vv[4] = {v.x, v.y, v.z, v.w};
        for (int j = 0; j < 4; ++j) {
            int idx = i + j;
            if (idx < N) offs[idx] = vv[j];
            else if (idx == N) offs[idx] = E;
        }
    }
    if ((tid & 127) == 0 && i < N) gcur[i >> 9] = v.x;
}

// ---------------------------------------------------------------------------
// Y = relu(A @ B^T + bias); A rows from A_lo (k<128) / A_hi (k>=128), bf16.
// B: [128][K] f32, converted during LDS staging. Col sum/sumsq -> striped
// fp64 slots: sum[slot*128+c], slot = blockIdx & 31.
template<int K>
__global__ __launch_bounds__(256) void gemm_bn(
    const unsigned short* __restrict__ A_lo,
    const unsigned short* __restrict__ A_hi,
    const float* __restrict__ B,
    const float* __restrict__ bias,
    float* __restrict__ Y,
    double* __restrict__ sum, double* __restrict__ sumsq, int N)
{
    constexpr int SA = 72;
    __shared__ unsigned short As[64 * SA];
    __shared__ unsigned short Bs[128 * SA];
    __shared__ float bsum_s[128], bsq_s[128];

    const int tid  = threadIdx.x;
    const int lane = tid & 63;
    const int wv   = tid >> 6;
    const int wr   = wv >> 1;
    const int wc   = wv & 1;
    const int m15  = lane & 15;
    const int quad = lane >> 4;
    const int r0   = blockIdx.x * 64;

    if (tid < 128) { bsum_s[tid] = 0.f; bsq_s[tid] = 0.f; }

    f32x4 acc[2][4];
#pragma unroll
    for (int rt = 0; rt < 2; ++rt)
#pragma unroll
        for (int ct = 0; ct < 4; ++ct)
            acc[rt][ct] = (f32x4){0.f, 0.f, 0.f, 0.f};

    for (int kc = 0; kc < K; kc += 64) {
        const unsigned short* Ap = (kc < 128) ? A_lo : A_hi;
        const int koff = kc & 127;
#pragma unroll
        for (int i = 0; i < 2; ++i) {
            int idx = i * 256 + tid;
            int row = idx >> 3, seg = idx & 7;
            int gr  = r0 + row; if (gr >= N) gr = N - 1;
            uint4 v = *(const uint4*)(Ap + (size_t)gr * 128 + koff + seg * 8);
            *(uint4*)(As + row * SA + seg * 8) = v;
        }
#pragma unroll
        for (int i = 0; i < 8; ++i) {
            int idx = i * 256 + tid;
            int row = idx >> 4, seg = idx & 15;
            float4 v = *(const float4*)(B + (size_t)row * K + kc + seg * 4);
            ushort4 o;
            o.x = f2bf(v.x); o.y = f2bf(v.y); o.z = f2bf(v.z); o.w = f2bf(v.w);
            *(ushort4*)(Bs + row * SA + seg * 4) = o;
        }
        __syncthreads();

#pragma unroll
        for (int ks = 0; ks < 64; ks += 32) {
            bf16x8 af[2], bfr[4];
#pragma unroll
            for (int rt = 0; rt < 2; ++rt)
                af[rt] = *(const bf16x8*)(As + (wr * 32 + rt * 16 + m15) * SA + ks + quad * 8);
#pragma unroll
            for (int ct = 0; ct < 4; ++ct)
                bfr[ct] = *(const bf16x8*)(Bs + (wc * 64 + ct * 16 + m15) * SA + ks + quad * 8);
#pragma unroll
            for (int rt = 0; rt < 2; ++rt)
#pragma unroll
                for (int ct = 0; ct < 4; ++ct)
                    acc[rt][ct] = __builtin_amdgcn_mfma_f32_16x16x32_bf16(
                        af[rt], bfr[ct], acc[rt][ct], 0, 0, 0);
        }
        __syncthreads();
    }

    // epilogue: +bias, relu, store, per-column sum/sumsq
#pragma unroll
    for (int ct = 0; ct < 4; ++ct) {
        int col = wc * 64 + ct * 16 + m15;
        float bz = bias[col];
        float s = 0.f, q = 0.f;
#pragma unroll
        for (int rt = 0; rt < 2; ++rt) {
#pragma unroll
            for (int reg = 0; reg < 4; ++reg) {
                int row = r0 + wr * 32 + rt * 16 + quad * 4 + reg;
                float v = fmaxf(acc[rt][ct][reg] + bz, 0.f);
                if (row < N) {
                    Y[(size_t)row * 128 + col] = v;
                } else {
                    v = 0.f;
                }
                s += v; q = fmaf(v, v, q);
            }
        }
        s += __shfl_xor(s, 16, 64); s += __shfl_xor(s, 32, 64);
        q += __shfl_xor(q, 16, 64); q += __shfl_xor(q, 32, 64);
        if (quad == 0) {
            atomicAdd(&bsum_s[col], s);
            atomicAdd(&bsq_s[col], q);
        }
    }
    __syncthreads();
    if (tid < 128) {
        const int slot = (blockIdx.x & (NSLOT - 1)) * 128;
        atomicAdd(&sum[slot + tid],   (double)bsum_s[tid]);
        atomicAdd(&sumsq[slot + tid], (double)bsq_s[tid]);
    }
}

// ---------------------------------------------------------------------------
// h = bf16(a[c]*y + b[c]); coefs from striped fp64 stats (reduce 32 slots).
__global__ __launch_bounds__(256) void apply_bn_bf16(
    const float* __restrict__ y,
    const double* __restrict__ sum, const double* __restrict__ sumsq,
    const float* __restrict__ gamma, const float* __restrict__ beta,
    unsigned short* __restrict__ h, int n, double invN)
{
    __shared__ float sa[128], sb[128];
    const int t = threadIdx.x;
    if (t < 128) {
        double ms = 0.0, qs = 0.0;
#pragma unroll
        for (int s = 0; s < NSLOT; ++s) {
            ms += sum[s * 128 + t];
            qs += sumsq[s * 128 + t];
        }
        float mean = (float)(ms * invN);
        float var  = (float)(qs * invN) - mean * mean;
        float sc = rsqrtf(var + BN_EPS) * gamma[t];
        sa[t] = sc;
        sb[t] = fmaf(-mean, sc, beta[t]);
    }
    __syncthreads();
    int i = (blockIdx.x * 256 + t) * 4;
    if (i >= n) return;
    int c = i & 127;
    float4 v = *(const float4*)(y + i);
    ushort4 o;
    o.x = f2bf(fmaf(sa[c],     v.x, sb[c]));
    o.y = f2bf(fmaf(sa[c + 1], v.y, sb[c + 1]));
    o.z = f2bf(fmaf(sa[c + 2], v.z, sb[c + 2]));
    o.w = f2bf(fmaf(sa[c + 3], v.w, sb[c + 3]));
    *(ushort4*)(h + i) = o;
}

// ---------------------------------------------------------------------------
// pass 1: bin edges into coarse buckets of 512 dsts (int4 records).
__global__ __launch_bounds__(256) void k_bin(
    const int* __restrict__ src, const int* __restrict__ dst,
    const float* __restrict__ w, int* __restrict__ gcur,
    int4* __restrict__ tmp, int E)
{
    __shared__ int hcnt[128];
    __shared__ int hbase[128];
    const int tid = threadIdx.x;
    if (tid < 128) hcnt[tid] = 0;
    __syncthreads();

    int d8[8], s8[8], slot8[8];
    float w8[8];
#pragma unroll
    for (int j = 0; j < 8; ++j) {
        int e = blockIdx.x * 2048 + j * 256 + tid;
        if (e < E) {
            d8[j] = dst[e]; s8[j] = src[e]; w8[j] = w[e];
            slot8[j] = atomicAdd(&hcnt[d8[j] >> 9], 1);
        } else d8[j] = -1;
    }
    __syncthreads();
    if (tid < 128 && hcnt[tid] > 0)
        hbase[tid] = atomicAdd(&gcur[tid], hcnt[tid]);
    __syncthreads();
#pragma unroll
    for (int j = 0; j < 8; ++j) {
        if (d8[j] >= 0) {
            int pos = hbase[d8[j] >> 9] + slot8[j];
            tmp[pos] = make_int4(s8[j], __float_as_int(w8[j]), d8[j], 0);
        }
    }
}

// pass 2: exact dst order within each bucket (L2-local scatter).
__global__ __launch_bounds__(256) void k_refine(
    const int4* __restrict__ tmp, const int* __restrict__ offs,
    int2* __restrict__ epack, int N)
{
    __shared__ int lcur[512];
    const int b    = blockIdx.x;
    const int d0   = b << 9;
    const int dlim = min(512, N - d0);
    for (int i = threadIdx.x; i < dlim; i += 256) lcur[i] = offs[d0 + i];
    __syncthreads();
    const int start = offs[d0];
    const int end   = offs[d0 + dlim];
    for (int p = start + threadIdx.x; p < end; p += 256) {
        int4 rec = tmp[p];
        int pos = atomicAdd(&lcur[rec.z - d0], 1);
        epack[pos] = make_int2(rec.x, rec.y);
    }
}

// ---------------------------------------------------------------------------
// One wave per dst row; h bf16 (bn applied). Writes agg only (bf16).
__global__ __launch_bounds__(256) void gather_agg(
    const unsigned short* __restrict__ h,
    const int* __restrict__ offs, const int2* __restrict__ epack,
    unsigned short* __restrict__ aggb, int N)
{
    const int r    = (int)((blockIdx.x * 256u + threadIdx.x) >> 6);
    const int lane = threadIdx.x & 63;
    if (r >= N) return;
    int p = offs[r];
    const int end = offs[r + 1];
    float nx = 0.f, ny = 0.f, den = 0.f;
    for (; p + 3 < end; p += 4) {
        int2 e0 = epack[p],     e1 = epack[p + 1];
        int2 e2 = epack[p + 2], e3 = epack[p + 3];
        uint32_t u0 = *(const uint32_t*)(h + (size_t)e0.x * 128 + 2 * lane);
        uint32_t u1 = *(const uint32_t*)(h + (size_t)e1.x * 128 + 2 * lane);
        uint32_t u2 = *(const uint32_t*)(h + (size_t)e2.x * 128 + 2 * lane);
        uint32_t u3 = *(const uint32_t*)(h + (size_t)e3.x * 128 + 2 * lane);
        float w0 = __int_as_float(e0.y), w1 = __int_as_float(e1.y);
        float w2 = __int_as_float(e2.y), w3 = __int_as_float(e3.y);
        nx = fmaf(w0, bf_lo(u0), nx); ny = fmaf(w0, bf_hi(u0), ny);
        nx = fmaf(w1, bf_lo(u1), nx); ny = fmaf(w1, bf_hi(u1), ny);
        nx = fmaf(w2, bf_lo(u2), nx); ny = fmaf(w2, bf_hi(u2), ny);
        nx = fmaf(w3, bf_lo(u3), nx); ny = fmaf(w3, bf_hi(u3), ny);
        den += (w0 + w1) + (w2 + w3);
    }
    for (; p < end; ++p) {
        int2 e0 = epack[p];
        float w0 = __int_as_float(e0.y);
        uint32_t u0 = *(const uint32_t*)(h + (size_t)e0.x * 128 + 2 * lane);
        nx = fmaf(w0, bf_lo(u0), nx); ny = fmaf(w0, bf_hi(u0), ny);
        den += w0;
    }
    float2 outv;
    if (den != 0.f) {
        float inv = 1.f / den;
        outv.x = nx * inv; outv.y = ny * inv;
    } else {
        uint32_t u = *(const uint32_t*)(h + (size_t)r * 128 + 2 * lane);
        outv.x = bf_lo(u); outv.y = bf_hi(u);
    }
    ushort2 ao; ao.x = f2bf(outv.x); ao.y = f2bf(outv.y);
    *(ushort2*)&aggb[(size_t)r * 128 + 2 * lane] = ao;
}

// ---------------------------------------------------------------------------
// bn2 affine (striped stats reduce) + row L2 normalize.
__global__ __launch_bounds__(256) void finalize(
    const float* __restrict__ Y2,
    const double* __restrict__ sum, const double* __restrict__ sumsq,
    const float* __restrict__ gamma, const float* __restrict__ beta,
    float* __restrict__ out, int N, double invN)
{
    __shared__ float sa[128], sb[128];
    const int t = threadIdx.x;
    if (t < 128) {
        double ms = 0.0, qs = 0.0;
#pragma unroll
        for (int s = 0; s < NSLOT; ++s) {
            ms += sum[s * 128 + t];
            qs += sumsq[s * 128 + t];
        }
        float mean = (float)(ms * invN);
        float var  = (float)(qs * invN) - mean * mean;
        float sc = rsqrtf(var + BN_EPS) * gamma[t];
        sa[t] = sc;
        sb[t] = fmaf(-mean, sc, beta[t]);
    }
    __syncthreads();
    const int row  = (int)((blockIdx.x * 256u + t) >> 6);
    const int lane = t & 63;
    if (row >= N) return;
    const size_t base = (size_t)row * 128;
    float v0 = fmaf(sa[lane],      Y2[base + lane],      sb[lane]);
    float v1 = fmaf(sa[lane + 64], Y2[base + lane + 64], sb[lane + 64]);
    float ss = fmaf(v0, v0, v1 * v1);
#pragma unroll
    for (int o = 32; o; o >>= 1) ss += __shfl_xor(ss, o, 64);
    float nrm = sqrtf(ss);
    float inv = (nrm == 0.f) ? 1.f : 1.f / nrm;
    out[base + lane]      = v0 * inv;
    out[base + lane + 64] = v1 * inv;
}

// ---------------------------------------------------------------------------
extern "C" void kernel_launch(void* const* d_in, const int* in_sizes, int n_in,
                              void* d_out, int out_size, void* d_ws, size_t ws_size,
                              hipStream_t stream)
{
    const float* feat   = (const float*)d_in[0];
    const float* w      = (const float*)d_in[1];
    const float* Q_w    = (const float*)d_in[2];
    const float* Q_b    = (const float*)d_in[3];
    const float* W_w    = (const float*)d_in[4];
    const float* W_b    = (const float*)d_in[5];
    const float* gamma2 = (const float*)d_in[6];
    const float* beta2  = (const float*)d_in[7];
    const int*   src    = (const int*)d_in[8];
    const int*   dst    = (const int*)d_in[9];

    const int N = in_sizes[0] / 128;   // 50000
    const int E = in_sizes[1];         // 800000

    const int SB = (N + 4095) / 4096;  // scan blocks (13)
    const int NP = SB * 4096;          // padded element count for scan

    // workspace layout
    float*          y1    = (float*)d_ws;                            // N*128 f32 (y1 then y2)
    unsigned short* featb = (unsigned short*)(y1 + (size_t)N * 128); // N*128 bf16
    unsigned short* aggb  = featb + (size_t)N * 128;                 // N*128 bf16
    unsigned short* h_bf  = aggb + (size_t)N * 128;                  // N*128 bf16
    int4*  tmp    = (int4*)(h_bf + (size_t)N * 128);                 // E (16B aligned)
    int2*  epack  = (int2*)(tmp + E);                                // E
    int*   offs   = (int*)(epack + E);                               // NP+4 (padded)
    int*   gcur   = offs + NP + 4;                                   // 128
    int*   bsum   = gcur + 128;                                      // 16
    double* stats = (double*)(bsum + 16);                            // 4*NSLOT*128 <- zeroed
    double* sum1   = stats;
    double* sumsq1 = stats + NSLOT * 128;
    double* sum2   = stats + 2 * NSLOT * 128;
    double* sumsq2 = stats + 3 * NSLOT * 128;
    int*   cnt    = (int*)(stats + 4 * NSLOT * 128);                 // NP  <- zeroed

    // zero stats + padded cnt (contiguous)
    hipMemsetAsync(stats, 0,
                   4 * NSLOT * 128 * sizeof(double) + (size_t)NP * sizeof(int),
                   stream);

    const double invN = 1.0 / (double)N;
    const int gemm_blocks = (N + 63) / 64;
    const int NB = (N + 511) >> 9;     // coarse buckets (98)
    const int CB = (N * 128 / 4 + 255) / 256;   // cast blocks in k_pre

    k_pre<<<CB + (E + 255) / 256, 256, 0, stream>>>(
        feat, featb, N * 128, dst, cnt, E, CB);
    k_scan_part<<<SB, 1024, 0, stream>>>(cnt, offs, bsum);
    k_scan_fix<<<SB, 1024, 0, stream>>>(offs, bsum, gcur, N, E);

    k_bin<<<(E + 2047) / 2048, 256, 0, stream>>>(src, dst, w, gcur, tmp, E);
    k_refine<<<NB, 256, 0, stream>>>(tmp, offs, epack, N);

    gemm_bn<128><<<gemm_blocks, 256, 0, stream>>>(
        featb, featb, Q_w, Q_b, y1, sum1, sumsq1, N);
    apply_bn_bf16<<<(N * 128 + 1023) / 1024, 256, 0, stream>>>(
        y1, sum1, sumsq1, gamma2, beta2, h_bf, N * 128, invN);

    gather_agg<<<(N * 64 + 255) / 256, 256, 0, stream>>>(h_bf, offs, epack, aggb, N);

    gemm_bn<256><<<gemm_blocks, 256, 0, stream>>>(
        featb, aggb, W_w, W_b, y1 /*=y2*/, sum2, sumsq2, N);
    finalize<<<(N * 64 + 255) / 256, 256, 0, stream>>>(
        y1, sum2, sumsq2, gamma2, beta2, (float*)d_out, N, invN);
}

// Round 8
// 265.822 us; speedup vs baseline: 1.2083x; 1.2083x over previous
//
#include <hip/hip_runtime.h>
#include <stdint.h>

// PinConv pipeline: bf16-MFMA GEMMs (fused colstats, striped fp64 atomics) +
// locality-binned CSR gather. Round 8: dedicated single-block bn_coef kernel
// reduces the 32 stat slots ONCE (round 7 recomputed it in every consumer
// block: 800MB of redundant L2 fp64 traffic in finalize alone).

#define BN_EPS 1e-5f
#define NSLOT 32

typedef __attribute__((ext_vector_type(8))) short bf16x8;
typedef __attribute__((ext_vector_type(4))) float f32x4;

static __device__ __forceinline__ unsigned short f2bf(float f) {
    uint32_t u = __builtin_bit_cast(uint32_t, f);
    u += 0x7fffu + ((u >> 16) & 1u);          // round-to-nearest-even
    return (unsigned short)(u >> 16);
}
static __device__ __forceinline__ float bf_lo(uint32_t u) {
    return __builtin_bit_cast(float, u << 16);
}
static __device__ __forceinline__ float bf_hi(uint32_t u) {
    return __builtin_bit_cast(float, u & 0xffff0000u);
}

// ---------------------------------------------------------------------------
// Fused: blocks [0,CB) cast feat f32->bf16; blocks [CB,..) histogram dst.
__global__ __launch_bounds__(256) void k_pre(
    const float* __restrict__ feat, unsigned short* __restrict__ featb, int nf,
    const int* __restrict__ dst, int* __restrict__ cnt, int E, int CB)
{
    if ((int)blockIdx.x < CB) {
        int i = (blockIdx.x * 256 + threadIdx.x) * 4;
        if (i + 3 < nf) {
            float4 v = *(const float4*)(feat + i);
            ushort4 o;
            o.x = f2bf(v.x); o.y = f2bf(v.y); o.z = f2bf(v.z); o.w = f2bf(v.w);
            *(ushort4*)(featb + i) = o;
        } else {
            for (int j = i; j < nf; ++j) featb[j] = f2bf(feat[j]);
        }
    } else {
        int e = (blockIdx.x - CB) * 256 + threadIdx.x;
        if (e < E) atomicAdd(&cnt[dst[e]], 1);
    }
}

// ---------------------------------------------------------------------------
// Scan phase 1: each block scans 4096 elems (1024 thr x int4), cnt zero-padded.
__global__ __launch_bounds__(1024) void k_scan_part(
    const int* __restrict__ cnt, int* __restrict__ offs,
    int* __restrict__ bsum)
{
    __shared__ int wsum[16];
    const int tid = threadIdx.x, lane = tid & 63, wv = tid >> 6;
    const int i = blockIdx.x * 4096 + tid * 4;
    int4 v = *(const int4*)(cnt + i);
    int s = v.x + v.y + v.z + v.w;
    int incl = s;
#pragma unroll
    for (int o = 1; o < 64; o <<= 1) {
        int t = __shfl_up(incl, o, 64);
        if (lane >= o) incl += t;
    }
    if (lane == 63) wsum[wv] = incl;
    __syncthreads();
    if (wv == 0 && lane < 16) {
        int t = wsum[lane];
        int ss = t;
#pragma unroll
        for (int o = 1; o < 16; o <<= 1) {
            int u = __shfl_up(ss, o, 64);
            if (lane >= o) ss += u;
        }
        wsum[lane] = ss - t;
        if (lane == 15 && bsum) bsum[blockIdx.x] = ss;
    }
    __syncthreads();
    int e0 = wsum[wv] + incl - s;
    int4 o;
    o.x = e0; o.y = e0 + v.x; o.z = o.y + v.y; o.w = o.z + v.z;
    *(int4*)(offs + i) = o;
}

// Scan phase 2: add block prefix, emit gcur bucket cursors, offs[N]=E.
__global__ __launch_bounds__(1024) void k_scan_fix(
    int* __restrict__ offs, const int* __restrict__ bsum,
    int* __restrict__ gcur, int N, int E)
{
    __shared__ int pre_s;
    const int tid = threadIdx.x;
    if (tid == 0) {
        int p = 0;
        for (int j = 0; j < (int)blockIdx.x; ++j) p += bsum[j];
        pre_s = p;
    }
    __syncthreads();
    const int pre = pre_s;
    const int i = blockIdx.x * 4096 + tid * 4;
    int4 v = *(const int4*)(offs + i);
    v.x += pre; v.y += pre; v.z += pre; v.w += pre;
    if (i + 3 < N) {
        *(int4*)(offs + i) = v;
    } else {
        int vv[4] = {v.x, v.y, v.z, v.w};
        for (int j = 0; j < 4; ++j) {
            int idx = i + j;
            if (idx < N) offs[idx] = vv[j];
            else if (idx == N) offs[idx] = E;
        }
    }
    if ((tid & 127) == 0 && i < N) gcur[i >> 9] = v.x;
}

// ---------------------------------------------------------------------------
// Y = relu(A @ B^T + bias); A rows from A_lo (k<128) / A_hi (k>=128), bf16.
// B: [128][K] f32, converted during LDS staging. Col sum/sumsq -> striped
// fp64 slots: sum[slot*128+c], slot = blockIdx & 31.
template<int K>
__global__ __launch_bounds__(256) void gemm_bn(
    const unsigned short* __restrict__ A_lo,
    const unsigned short* __restrict__ A_hi,
    const float* __restrict__ B,
    const float* __restrict__ bias,
    float* __restrict__ Y,
    double* __restrict__ sum, double* __restrict__ sumsq, int N)
{
    constexpr int SA = 72;
    __shared__ unsigned short As[64 * SA];
    __shared__ unsigned short Bs[128 * SA];
    __shared__ float bsum_s[128], bsq_s[128];

    const int tid  = threadIdx.x;
    const int lane = tid & 63;
    const int wv   = tid >> 6;
    const int wr   = wv >> 1;
    const int wc   = wv & 1;
    const int m15  = lane & 15;
    const int quad = lane >> 4;
    const int r0   = blockIdx.x * 64;

    if (tid < 128) { bsum_s[tid] = 0.f; bsq_s[tid] = 0.f; }

    f32x4 acc[2][4];
#pragma unroll
    for (int rt = 0; rt < 2; ++rt)
#pragma unroll
        for (int ct = 0; ct < 4; ++ct)
            acc[rt][ct] = (f32x4){0.f, 0.f, 0.f, 0.f};

    for (int kc = 0; kc < K; kc += 64) {
        const unsigned short* Ap = (kc < 128) ? A_lo : A_hi;
        const int koff = kc & 127;
#pragma unroll
        for (int i = 0; i < 2; ++i) {
            int idx = i * 256 + tid;
            int row = idx >> 3, seg = idx & 7;
            int gr  = r0 + row; if (gr >= N) gr = N - 1;
            uint4 v = *(const uint4*)(Ap + (size_t)gr * 128 + koff + seg * 8);
            *(uint4*)(As + row * SA + seg * 8) = v;
        }
#pragma unroll
        for (int i = 0; i < 8; ++i) {
            int idx = i * 256 + tid;
            int row = idx >> 4, seg = idx & 15;
            float4 v = *(const float4*)(B + (size_t)row * K + kc + seg * 4);
            ushort4 o;
            o.x = f2bf(v.x); o.y = f2bf(v.y); o.z = f2bf(v.z); o.w = f2bf(v.w);
            *(ushort4*)(Bs + row * SA + seg * 4) = o;
        }
        __syncthreads();

#pragma unroll
        for (int ks = 0; ks < 64; ks += 32) {
            bf16x8 af[2], bfr[4];
#pragma unroll
            for (int rt = 0; rt < 2; ++rt)
                af[rt] = *(const bf16x8*)(As + (wr * 32 + rt * 16 + m15) * SA + ks + quad * 8);
#pragma unroll
            for (int ct = 0; ct < 4; ++ct)
                bfr[ct] = *(const bf16x8*)(Bs + (wc * 64 + ct * 16 + m15) * SA + ks + quad * 8);
#pragma unroll
            for (int rt = 0; rt < 2; ++rt)
#pragma unroll
                for (int ct = 0; ct < 4; ++ct)
                    acc[rt][ct] = __builtin_amdgcn_mfma_f32_16x16x32_bf16(
                        af[rt], bfr[ct], acc[rt][ct], 0, 0, 0);
        }
        __syncthreads();
    }

    // epilogue: +bias, relu, store, per-column sum/sumsq
#pragma unroll
    for (int ct = 0; ct < 4; ++ct) {
        int col = wc * 64 + ct * 16 + m15;
        float bz = bias[col];
        float s = 0.f, q = 0.f;
#pragma unroll
        for (int rt = 0; rt < 2; ++rt) {
#pragma unroll
            for (int reg = 0; reg < 4; ++reg) {
                int row = r0 + wr * 32 + rt * 16 + quad * 4 + reg;
                float v = fmaxf(acc[rt][ct][reg] + bz, 0.f);
                if (row < N) {
                    Y[(size_t)row * 128 + col] = v;
                } else {
                    v = 0.f;
                }
                s += v; q = fmaf(v, v, q);
            }
        }
        s += __shfl_xor(s, 16, 64); s += __shfl_xor(s, 32, 64);
        q += __shfl_xor(q, 16, 64); q += __shfl_xor(q, 32, 64);
        if (quad == 0) {
            atomicAdd(&bsum_s[col], s);
            atomicAdd(&bsq_s[col], q);
        }
    }
    __syncthreads();
    if (tid < 128) {
        const int slot = (blockIdx.x & (NSLOT - 1)) * 128;
        atomicAdd(&sum[slot + tid],   (double)bsum_s[tid]);
        atomicAdd(&sumsq[slot + tid], (double)bsq_s[tid]);
    }
}

// ---------------------------------------------------------------------------
// Single block: reduce 32 slots -> bn affine coefs a[128], b[128].
__global__ __launch_bounds__(128) void bn_coef(
    const double* __restrict__ sum, const double* __restrict__ sumsq,
    const float* __restrict__ gamma, const float* __restrict__ beta,
    float* __restrict__ a, float* __restrict__ b, double invN)
{
    const int t = threadIdx.x;  // 128
    double ms = 0.0, qs = 0.0;
#pragma unroll
    for (int s = 0; s < NSLOT; ++s) {
        ms += sum[s * 128 + t];
        qs += sumsq[s * 128 + t];
    }
    float mean = (float)(ms * invN);
    float var  = (float)(qs * invN) - mean * mean;
    float sc = rsqrtf(var + BN_EPS) * gamma[t];
    a[t] = sc;
    b[t] = fmaf(-mean, sc, beta[t]);
}

// ---------------------------------------------------------------------------
// h = bf16(a[c]*y + b[c]); coefs precomputed.
__global__ __launch_bounds__(256) void apply_bn_bf16(
    const float* __restrict__ y,
    const float* __restrict__ a, const float* __restrict__ b,
    unsigned short* __restrict__ h, int n)
{
    int i = (blockIdx.x * 256 + threadIdx.x) * 4;
    if (i >= n) return;
    int c = i & 127;
    float4 v  = *(const float4*)(y + i);
    float4 av = *(const float4*)(a + c);
    float4 bv = *(const float4*)(b + c);
    ushort4 o;
    o.x = f2bf(fmaf(av.x, v.x, bv.x));
    o.y = f2bf(fmaf(av.y, v.y, bv.y));
    o.z = f2bf(fmaf(av.z, v.z, bv.z));
    o.w = f2bf(fmaf(av.w, v.w, bv.w));
    *(ushort4*)(h + i) = o;
}

// ---------------------------------------------------------------------------
// pass 1: bin edges into coarse buckets of 512 dsts (int4 records).
__global__ __launch_bounds__(256) void k_bin(
    const int* __restrict__ src, const int* __restrict__ dst,
    const float* __restrict__ w, int* __restrict__ gcur,
    int4* __restrict__ tmp, int E)
{
    __shared__ int hcnt[128];
    __shared__ int hbase[128];
    const int tid = threadIdx.x;
    if (tid < 128) hcnt[tid] = 0;
    __syncthreads();

    int d8[8], s8[8], slot8[8];
    float w8[8];
#pragma unroll
    for (int j = 0; j < 8; ++j) {
        int e = blockIdx.x * 2048 + j * 256 + tid;
        if (e < E) {
            d8[j] = dst[e]; s8[j] = src[e]; w8[j] = w[e];
            slot8[j] = atomicAdd(&hcnt[d8[j] >> 9], 1);
        } else d8[j] = -1;
    }
    __syncthreads();
    if (tid < 128 && hcnt[tid] > 0)
        hbase[tid] = atomicAdd(&gcur[tid], hcnt[tid]);
    __syncthreads();
#pragma unroll
    for (int j = 0; j < 8; ++j) {
        if (d8[j] >= 0) {
            int pos = hbase[d8[j] >> 9] + slot8[j];
            tmp[pos] = make_int4(s8[j], __float_as_int(w8[j]), d8[j], 0);
        }
    }
}

// pass 2: exact dst order within each bucket (L2-local scatter).
__global__ __launch_bounds__(256) void k_refine(
    const int4* __restrict__ tmp, const int* __restrict__ offs,
    int2* __restrict__ epack, int N)
{
    __shared__ int lcur[512];
    const int b    = blockIdx.x;
    const int d0   = b << 9;
    const int dlim = min(512, N - d0);
    for (int i = threadIdx.x; i < dlim; i += 256) lcur[i] = offs[d0 + i];
    __syncthreads();
    const int start = offs[d0];
    const int end   = offs[d0 + dlim];
    for (int p = start + threadIdx.x; p < end; p += 256) {
        int4 rec = tmp[p];
        int pos = atomicAdd(&lcur[rec.z - d0], 1);
        epack[pos] = make_int2(rec.x, rec.y);
    }
}

// ---------------------------------------------------------------------------
// One wave per dst row; h bf16 (bn applied). Writes agg only (bf16).
__global__ __launch_bounds__(256) void gather_agg(
    const unsigned short* __restrict__ h,
    const int* __restrict__ offs, const int2* __restrict__ epack,
    unsigned short* __restrict__ aggb, int N)
{
    const int r    = (int)((blockIdx.x * 256u + threadIdx.x) >> 6);
    const int lane = threadIdx.x & 63;
    if (r >= N) return;
    int p = offs[r];
    const int end = offs[r + 1];
    float nx = 0.f, ny = 0.f, den = 0.f;
    for (; p + 3 < end; p += 4) {
        int2 e0 = epack[p],     e1 = epack[p + 1];
        int2 e2 = epack[p + 2], e3 = epack[p + 3];
        uint32_t u0 = *(const uint32_t*)(h + (size_t)e0.x * 128 + 2 * lane);
        uint32_t u1 = *(const uint32_t*)(h + (size_t)e1.x * 128 + 2 * lane);
        uint32_t u2 = *(const uint32_t*)(h + (size_t)e2.x * 128 + 2 * lane);
        uint32_t u3 = *(const uint32_t*)(h + (size_t)e3.x * 128 + 2 * lane);
        float w0 = __int_as_float(e0.y), w1 = __int_as_float(e1.y);
        float w2 = __int_as_float(e2.y), w3 = __int_as_float(e3.y);
        nx = fmaf(w0, bf_lo(u0), nx); ny = fmaf(w0, bf_hi(u0), ny);
        nx = fmaf(w1, bf_lo(u1), nx); ny = fmaf(w1, bf_hi(u1), ny);
        nx = fmaf(w2, bf_lo(u2), nx); ny = fmaf(w2, bf_hi(u2), ny);
        nx = fmaf(w3, bf_lo(u3), nx); ny = fmaf(w3, bf_hi(u3), ny);
        den += (w0 + w1) + (w2 + w3);
    }
    for (; p < end; ++p) {
        int2 e0 = epack[p];
        float w0 = __int_as_float(e0.y);
        uint32_t u0 = *(const uint32_t*)(h + (size_t)e0.x * 128 + 2 * lane);
        nx = fmaf(w0, bf_lo(u0), nx); ny = fmaf(w0, bf_hi(u0), ny);
        den += w0;
    }
    float2 outv;
    if (den != 0.f) {
        float inv = 1.f / den;
        outv.x = nx * inv; outv.y = ny * inv;
    } else {
        uint32_t u = *(const uint32_t*)(h + (size_t)r * 128 + 2 * lane);
        outv.x = bf_lo(u); outv.y = bf_hi(u);
    }
    ushort2 ao; ao.x = f2bf(outv.x); ao.y = f2bf(outv.y);
    *(ushort2*)&aggb[(size_t)r * 128 + 2 * lane] = ao;
}

// ---------------------------------------------------------------------------
// bn2 affine (precomputed coefs) + row L2 normalize.
__global__ __launch_bounds__(256) void finalize(
    const float* __restrict__ Y2,
    const float* __restrict__ a, const float* __restrict__ b,
    float* __restrict__ out, int N)
{
    __shared__ float sa[128], sb[128];
    const int t = threadIdx.x;
    if (t < 128) { sa[t] = a[t]; sb[t] = b[t]; }
    __syncthreads();
    const int row  = (int)((blockIdx.x * 256u + t) >> 6);
    const int lane = t & 63;
    if (row >= N) return;
    const size_t base = (size_t)row * 128;
    float v0 = fmaf(sa[lane],      Y2[base + lane],      sb[lane]);
    float v1 = fmaf(sa[lane + 64], Y2[base + lane + 64], sb[lane + 64]);
    float ss = fmaf(v0, v0, v1 * v1);
#pragma unroll
    for (int o = 32; o; o >>= 1) ss += __shfl_xor(ss, o, 64);
    float nrm = sqrtf(ss);
    float inv = (nrm == 0.f) ? 1.f : 1.f / nrm;
    out[base + lane]      = v0 * inv;
    out[base + lane + 64] = v1 * inv;
}

// ---------------------------------------------------------------------------
extern "C" void kernel_launch(void* const* d_in, const int* in_sizes, int n_in,
                              void* d_out, int out_size, void* d_ws, size_t ws_size,
                              hipStream_t stream)
{
    const float* feat   = (const float*)d_in[0];
    const float* w      = (const float*)d_in[1];
    const float* Q_w    = (const float*)d_in[2];
    const float* Q_b    = (const float*)d_in[3];
    const float* W_w    = (const float*)d_in[4];
    const float* W_b    = (const float*)d_in[5];
    const float* gamma2 = (const float*)d_in[6];
    const float* beta2  = (const float*)d_in[7];
    const int*   src    = (const int*)d_in[8];
    const int*   dst    = (const int*)d_in[9];

    const int N = in_sizes[0] / 128;   // 50000
    const int E = in_sizes[1];         // 800000

    const int SB = (N + 4095) / 4096;  // scan blocks (13)
    const int NP = SB * 4096;          // padded element count for scan

    // workspace layout
    float*          y1    = (float*)d_ws;                            // N*128 f32 (y1 then y2)
    unsigned short* featb = (unsigned short*)(y1 + (size_t)N * 128); // N*128 bf16
    unsigned short* aggb  = featb + (size_t)N * 128;                 // N*128 bf16
    unsigned short* h_bf  = aggb + (size_t)N * 128;                  // N*128 bf16
    int4*  tmp    = (int4*)(h_bf + (size_t)N * 128);                 // E (16B aligned)
    int2*  epack  = (int2*)(tmp + E);                                // E
    int*   offs   = (int*)(epack + E);                               // NP+4 (padded)
    int*   gcur   = offs + NP + 4;                                   // 128
    int*   bsum   = gcur + 128;                                      // 16
    float* coefs  = (float*)(bsum + 16);                             // 512
    float* a1 = coefs, *b1 = coefs + 128, *a2 = coefs + 256, *b2 = coefs + 384;
    double* stats = (double*)(coefs + 512);                          // 4*NSLOT*128 <- zeroed
    double* sum1   = stats;
    double* sumsq1 = stats + NSLOT * 128;
    double* sum2   = stats + 2 * NSLOT * 128;
    double* sumsq2 = stats + 3 * NSLOT * 128;
    int*   cnt    = (int*)(stats + 4 * NSLOT * 128);                 // NP  <- zeroed

    // zero stats + padded cnt (contiguous)
    hipMemsetAsync(stats, 0,
                   4 * NSLOT * 128 * sizeof(double) + (size_t)NP * sizeof(int),
                   stream);

    const double invN = 1.0 / (double)N;
    const int gemm_blocks = (N + 63) / 64;
    const int NB = (N + 511) >> 9;     // coarse buckets (98)
    const int CB = (N * 128 / 4 + 255) / 256;   // cast blocks in k_pre

    k_pre<<<CB + (E + 255) / 256, 256, 0, stream>>>(
        feat, featb, N * 128, dst, cnt, E, CB);
    k_scan_part<<<SB, 1024, 0, stream>>>(cnt, offs, bsum);
    k_scan_fix<<<SB, 1024, 0, stream>>>(offs, bsum, gcur, N, E);

    k_bin<<<(E + 2047) / 2048, 256, 0, stream>>>(src, dst, w, gcur, tmp, E);
    k_refine<<<NB, 256, 0, stream>>>(tmp, offs, epack, N);

    gemm_bn<128><<<gemm_blocks, 256, 0, stream>>>(
        featb, featb, Q_w, Q_b, y1, sum1, sumsq1, N);
    bn_coef<<<1, 128, 0, stream>>>(sum1, sumsq1, gamma2, beta2, a1, b1, invN);
    apply_bn_bf16<<<(N * 128 + 1023) / 1024, 256, 0, stream>>>(
        y1, a1, b1, h_bf, N * 128);

    gather_agg<<<(N * 64 + 255) / 256, 256, 0, stream>>>(h_bf, offs, epack, aggb, N);

    gemm_bn<256><<<gemm_blocks, 256, 0, stream>>>(
        featb, aggb, W_w, W_b, y1 /*=y2*/, sum2, sumsq2, N);
    bn_coef<<<1, 128, 0, stream>>>(sum2, sumsq2, gamma2, beta2, a2, b2, invN);
    finalize<<<(N * 64 + 255) / 256, 256, 0, stream>>>(
        y1, a2, b2, (float*)d_out, N);
}

// Round 9
// 254.309 us; speedup vs baseline: 1.2630x; 1.0453x over previous
//
#include <hip/hip_runtime.h>
#include <stdint.h>

// PinConv pipeline: bf16-MFMA GEMMs (fused colstats, striped fp64 atomics) +
// locality-binned CSR gather. Round 9: exact dst histogram + 50K scan
// ELIMINATED — coarse 98-bucket LDS histogram (k_pre) + 1-block bucket scan
// (k_coffs) + k_refine derives per-dst offsets in LDS from binned records.
// Kills the 800K random global atomics that made k_pre 43.7us.

#define BN_EPS 1e-5f
#define NSLOT 32

typedef __attribute__((ext_vector_type(8))) short bf16x8;
typedef __attribute__((ext_vector_type(4))) float f32x4;

static __device__ __forceinline__ unsigned short f2bf(float f) {
    uint32_t u = __builtin_bit_cast(uint32_t, f);
    u += 0x7fffu + ((u >> 16) & 1u);          // round-to-nearest-even
    return (unsigned short)(u >> 16);
}
static __device__ __forceinline__ float bf_lo(uint32_t u) {
    return __builtin_bit_cast(float, u << 16);
}
static __device__ __forceinline__ float bf_hi(uint32_t u) {
    return __builtin_bit_cast(float, u & 0xffff0000u);
}

// ---------------------------------------------------------------------------
// Fused: blocks [0,CB) cast feat f32->bf16; blocks [CB,..) coarse-histogram
// dst into 512-wide buckets (LDS-aggregated, <=98 global atomics per block).
__global__ __launch_bounds__(256) void k_pre(
    const float* __restrict__ feat, unsigned short* __restrict__ featb, int nf,
    const int* __restrict__ dst, int* __restrict__ ccnt, int E, int CB)
{
    if ((int)blockIdx.x < CB) {
        int i = (blockIdx.x * 256 + threadIdx.x) * 4;
        if (i + 3 < nf) {
            float4 v = *(const float4*)(feat + i);
            ushort4 o;
            o.x = f2bf(v.x); o.y = f2bf(v.y); o.z = f2bf(v.z); o.w = f2bf(v.w);
            *(ushort4*)(featb + i) = o;
        } else {
            for (int j = i; j < nf; ++j) featb[j] = f2bf(feat[j]);
        }
    } else {
        __shared__ int hcnt[128];
        const int tid = threadIdx.x;
        if (tid < 128) hcnt[tid] = 0;
        __syncthreads();
        const int base_e = (blockIdx.x - CB) * 2048;
#pragma unroll
        for (int j = 0; j < 8; ++j) {
            int e = base_e + j * 256 + tid;
            if (e < E) atomicAdd(&hcnt[dst[e] >> 9], 1);
        }
        __syncthreads();
        if (tid < 128 && hcnt[tid] > 0) atomicAdd(&ccnt[tid], hcnt[tid]);
    }
}

// ---------------------------------------------------------------------------
// Single block: exclusive scan of 128 bucket counts -> coffs[129], gcur,
// and offs[N] = E.
__global__ __launch_bounds__(128) void k_coffs(
    const int* __restrict__ ccnt, int* __restrict__ coffs,
    int* __restrict__ gcur, int* __restrict__ offs, int N, int E)
{
    __shared__ int w0sum;
    const int t = threadIdx.x;             // 128 threads, 2 waves
    const int lane = t & 63, wv = t >> 6;
    int v = ccnt[t];
    int incl = v;
#pragma unroll
    for (int o = 1; o < 64; o <<= 1) {
        int u = __shfl_up(incl, o, 64);
        if (lane >= o) incl += u;
    }
    if (wv == 0 && lane == 63) w0sum = incl;
    __syncthreads();
    int excl = incl - v + (wv ? w0sum : 0);
    coffs[t] = excl;
    gcur[t]  = excl;
    if (t == 127) { coffs[128] = excl + v; offs[N] = E; }
}

// ---------------------------------------------------------------------------
// Y = relu(A @ B^T + bias); A rows from A_lo (k<128) / A_hi (k>=128), bf16.
// B: [128][K] f32, converted during LDS staging. Col sum/sumsq -> striped
// fp64 slots: sum[slot*128+c], slot = blockIdx & 31.
template<int K>
__global__ __launch_bounds__(256) void gemm_bn(
    const unsigned short* __restrict__ A_lo,
    const unsigned short* __restrict__ A_hi,
    const float* __restrict__ B,
    const float* __restrict__ bias,
    float* __restrict__ Y,
    double* __restrict__ sum, double* __restrict__ sumsq, int N)
{
    constexpr int SA = 72;
    __shared__ unsigned short As[64 * SA];
    __shared__ unsigned short Bs[128 * SA];
    __shared__ float bsum_s[128], bsq_s[128];

    const int tid  = threadIdx.x;
    const int lane = tid & 63;
    const int wv   = tid >> 6;
    const int wr   = wv >> 1;
    const int wc   = wv & 1;
    const int m15  = lane & 15;
    const int quad = lane >> 4;
    const int r0   = blockIdx.x * 64;

    if (tid < 128) { bsum_s[tid] = 0.f; bsq_s[tid] = 0.f; }

    f32x4 acc[2][4];
#pragma unroll
    for (int rt = 0; rt < 2; ++rt)
#pragma unroll
        for (int ct = 0; ct < 4; ++ct)
            acc[rt][ct] = (f32x4){0.f, 0.f, 0.f, 0.f};

    for (int kc = 0; kc < K; kc += 64) {
        const unsigned short* Ap = (kc < 128) ? A_lo : A_hi;
        const int koff = kc & 127;
#pragma unroll
        for (int i = 0; i < 2; ++i) {
            int idx = i * 256 + tid;
            int row = idx >> 3, seg = idx & 7;
            int gr  = r0 + row; if (gr >= N) gr = N - 1;
            uint4 v = *(const uint4*)(Ap + (size_t)gr * 128 + koff + seg * 8);
            *(uint4*)(As + row * SA + seg * 8) = v;
        }
#pragma unroll
        for (int i = 0; i < 8; ++i) {
            int idx = i * 256 + tid;
            int row = idx >> 4, seg = idx & 15;
            float4 v = *(const float4*)(B + (size_t)row * K + kc + seg * 4);
            ushort4 o;
            o.x = f2bf(v.x); o.y = f2bf(v.y); o.z = f2bf(v.z); o.w = f2bf(v.w);
            *(ushort4*)(Bs + row * SA + seg * 4) = o;
        }
        __syncthreads();

#pragma unroll
        for (int ks = 0; ks < 64; ks += 32) {
            bf16x8 af[2], bfr[4];
#pragma unroll
            for (int rt = 0; rt < 2; ++rt)
                af[rt] = *(const bf16x8*)(As + (wr * 32 + rt * 16 + m15) * SA + ks + quad * 8);
#pragma unroll
            for (int ct = 0; ct < 4; ++ct)
                bfr[ct] = *(const bf16x8*)(Bs + (wc * 64 + ct * 16 + m15) * SA + ks + quad * 8);
#pragma unroll
            for (int rt = 0; rt < 2; ++rt)
#pragma unroll
                for (int ct = 0; ct < 4; ++ct)
                    acc[rt][ct] = __builtin_amdgcn_mfma_f32_16x16x32_bf16(
                        af[rt], bfr[ct], acc[rt][ct], 0, 0, 0);
        }
        __syncthreads();
    }

    // epilogue: +bias, relu, store, per-column sum/sumsq
#pragma unroll
    for (int ct = 0; ct < 4; ++ct) {
        int col = wc * 64 + ct * 16 + m15;
        float bz = bias[col];
        float s = 0.f, q = 0.f;
#pragma unroll
        for (int rt = 0; rt < 2; ++rt) {
#pragma unroll
            for (int reg = 0; reg < 4; ++reg) {
                int row = r0 + wr * 32 + rt * 16 + quad * 4 + reg;
                float v = fmaxf(acc[rt][ct][reg] + bz, 0.f);
                if (row < N) {
                    Y[(size_t)row * 128 + col] = v;
                } else {
                    v = 0.f;
                }
                s += v; q = fmaf(v, v, q);
            }
        }
        s += __shfl_xor(s, 16, 64); s += __shfl_xor(s, 32, 64);
        q += __shfl_xor(q, 16, 64); q += __shfl_xor(q, 32, 64);
        if (quad == 0) {
            atomicAdd(&bsum_s[col], s);
            atomicAdd(&bsq_s[col], q);
        }
    }
    __syncthreads();
    if (tid < 128) {
        const int slot = (blockIdx.x & (NSLOT - 1)) * 128;
        atomicAdd(&sum[slot + tid],   (double)bsum_s[tid]);
        atomicAdd(&sumsq[slot + tid], (double)bsq_s[tid]);
    }
}

// ---------------------------------------------------------------------------
// Single block: reduce 32 slots -> bn affine coefs a[128], b[128].
__global__ __launch_bounds__(128) void bn_coef(
    const double* __restrict__ sum, const double* __restrict__ sumsq,
    const float* __restrict__ gamma, const float* __restrict__ beta,
    float* __restrict__ a, float* __restrict__ b, double invN)
{
    const int t = threadIdx.x;  // 128
    double ms = 0.0, qs = 0.0;
#pragma unroll
    for (int s = 0; s < NSLOT; ++s) {
        ms += sum[s * 128 + t];
        qs += sumsq[s * 128 + t];
    }
    float mean = (float)(ms * invN);
    float var  = (float)(qs * invN) - mean * mean;
    float sc = rsqrtf(var + BN_EPS) * gamma[t];
    a[t] = sc;
    b[t] = fmaf(-mean, sc, beta[t]);
}

// ---------------------------------------------------------------------------
// h = bf16(a[c]*y + b[c]); coefs precomputed.
__global__ __launch_bounds__(256) void apply_bn_bf16(
    const float* __restrict__ y,
    const float* __restrict__ a, const float* __restrict__ b,
    unsigned short* __restrict__ h, int n)
{
    int i = (blockIdx.x * 256 + threadIdx.x) * 4;
    if (i >= n) return;
    int c = i & 127;
    float4 v  = *(const float4*)(y + i);
    float4 av = *(const float4*)(a + c);
    float4 bv = *(const float4*)(b + c);
    ushort4 o;
    o.x = f2bf(fmaf(av.x, v.x, bv.x));
    o.y = f2bf(fmaf(av.y, v.y, bv.y));
    o.z = f2bf(fmaf(av.z, v.z, bv.z));
    o.w = f2bf(fmaf(av.w, v.w, bv.w));
    *(ushort4*)(h + i) = o;
}

// ---------------------------------------------------------------------------
// pass 1: bin edges into coarse buckets of 512 dsts (int4 records).
__global__ __launch_bounds__(256) void k_bin(
    const int* __restrict__ src, const int* __restrict__ dst,
    const float* __restrict__ w, int* __restrict__ gcur,
    int4* __restrict__ tmp, int E)
{
    __shared__ int hcnt[128];
    __shared__ int hbase[128];
    const int tid = threadIdx.x;
    if (tid < 128) hcnt[tid] = 0;
    __syncthreads();

    int d8[8], s8[8], slot8[8];
    float w8[8];
#pragma unroll
    for (int j = 0; j < 8; ++j) {
        int e = blockIdx.x * 2048 + j * 256 + tid;
        if (e < E) {
            d8[j] = dst[e]; s8[j] = src[e]; w8[j] = w[e];
            slot8[j] = atomicAdd(&hcnt[d8[j] >> 9], 1);
        } else d8[j] = -1;
    }
    __syncthreads();
    if (tid < 128 && hcnt[tid] > 0)
        hbase[tid] = atomicAdd(&gcur[tid], hcnt[tid]);
    __syncthreads();
#pragma unroll
    for (int j = 0; j < 8; ++j) {
        if (d8[j] >= 0) {
            int pos = hbase[d8[j] >> 9] + slot8[j];
            tmp[pos] = make_int4(s8[j], __float_as_int(w8[j]), d8[j], 0);
        }
    }
}

// ---------------------------------------------------------------------------
// pass 2: per bucket — count per-dst in LDS, scan (+coffs base), write the
// offs slice, then scatter records to epack in exact dst order.
__global__ __launch_bounds__(256) void k_refine(
    const int4* __restrict__ tmp, const int* __restrict__ coffs,
    int* __restrict__ offs, int2* __restrict__ epack, int N)
{
    __shared__ int hist[512];      // counts, then reused as cursors
    __shared__ int wpre[4];
    const int b    = blockIdx.x;
    const int d0   = b << 9;
    const int dlim = min(512, N - d0);
    const int tid  = threadIdx.x;
    const int lane = tid & 63, wv = tid >> 6;
    const int start = coffs[b];
    const int end   = coffs[b + 1];

    hist[tid] = 0; hist[tid + 256] = 0;
    __syncthreads();

    for (int p = start + tid; p < end; p += 256)
        atomicAdd(&hist[tmp[p].z - d0], 1);
    __syncthreads();

    // exclusive scan of hist[0..511]: each thread owns elems 2t, 2t+1
    int v0 = hist[2 * tid], v1 = hist[2 * tid + 1];
    int s = v0 + v1;
    int incl = s;
#pragma unroll
    for (int o = 1; o < 64; o <<= 1) {
        int t = __shfl_up(incl, o, 64);
        if (lane >= o) incl += t;
    }
    if (lane == 63) wpre[wv] = incl;
    __syncthreads();
    if (tid == 0) {
        int r = 0;
#pragma unroll
        for (int i = 0; i < 4; ++i) { int t = wpre[i]; wpre[i] = r; r += t; }
    }
    __syncthreads();
    int e0 = start + wpre[wv] + incl - s;   // exclusive prefix of elem 2t
    if (2 * tid < dlim)     offs[d0 + 2 * tid]     = e0;
    if (2 * tid + 1 < dlim) offs[d0 + 2 * tid + 1] = e0 + v0;
    hist[2 * tid]     = e0;                 // reuse as cursors
    hist[2 * tid + 1] = e0 + v0;
    __syncthreads();

    for (int p = start + tid; p < end; p += 256) {
        int4 rec = tmp[p];
        int pos = atomicAdd(&hist[rec.z - d0], 1);
        epack[pos] = make_int2(rec.x, rec.y);
    }
}

// ---------------------------------------------------------------------------
// One wave per dst row; h bf16 (bn applied). Writes agg only (bf16).
__global__ __launch_bounds__(256) void gather_agg(
    const unsigned short* __restrict__ h,
    const int* __restrict__ offs, const int2* __restrict__ epack,
    unsigned short* __restrict__ aggb, int N)
{
    const int r    = (int)((blockIdx.x * 256u + threadIdx.x) >> 6);
    const int lane = threadIdx.x & 63;
    if (r >= N) return;
    int p = offs[r];
    const int end = offs[r + 1];
    float nx = 0.f, ny = 0.f, den = 0.f;
    for (; p + 3 < end; p += 4) {
        int2 e0 = epack[p],     e1 = epack[p + 1];
        int2 e2 = epack[p + 2], e3 = epack[p + 3];
        uint32_t u0 = *(const uint32_t*)(h + (size_t)e0.x * 128 + 2 * lane);
        uint32_t u1 = *(const uint32_t*)(h + (size_t)e1.x * 128 + 2 * lane);
        uint32_t u2 = *(const uint32_t*)(h + (size_t)e2.x * 128 + 2 * lane);
        uint32_t u3 = *(const uint32_t*)(h + (size_t)e3.x * 128 + 2 * lane);
        float w0 = __int_as_float(e0.y), w1 = __int_as_float(e1.y);
        float w2 = __int_as_float(e2.y), w3 = __int_as_float(e3.y);
        nx = fmaf(w0, bf_lo(u0), nx); ny = fmaf(w0, bf_hi(u0), ny);
        nx = fmaf(w1, bf_lo(u1), nx); ny = fmaf(w1, bf_hi(u1), ny);
        nx = fmaf(w2, bf_lo(u2), nx); ny = fmaf(w2, bf_hi(u2), ny);
        nx = fmaf(w3, bf_lo(u3), nx); ny = fmaf(w3, bf_hi(u3), ny);
        den += (w0 + w1) + (w2 + w3);
    }
    for (; p < end; ++p) {
        int2 e0 = epack[p];
        float w0 = __int_as_float(e0.y);
        uint32_t u0 = *(const uint32_t*)(h + (size_t)e0.x * 128 + 2 * lane);
        nx = fmaf(w0, bf_lo(u0), nx); ny = fmaf(w0, bf_hi(u0), ny);
        den += w0;
    }
    float2 outv;
    if (den != 0.f) {
        float inv = 1.f / den;
        outv.x = nx * inv; outv.y = ny * inv;
    } else {
        uint32_t u = *(const uint32_t*)(h + (size_t)r * 128 + 2 * lane);
        outv.x = bf_lo(u); outv.y = bf_hi(u);
    }
    ushort2 ao; ao.x = f2bf(outv.x); ao.y = f2bf(outv.y);
    *(ushort2*)&aggb[(size_t)r * 128 + 2 * lane] = ao;
}

// ---------------------------------------------------------------------------
// bn2 affine (precomputed coefs) + row L2 normalize.
__global__ __launch_bounds__(256) void finalize(
    const float* __restrict__ Y2,
    const float* __restrict__ a, const float* __restrict__ b,
    float* __restrict__ out, int N)
{
    __shared__ float sa[128], sb[128];
    const int t = threadIdx.x;
    if (t < 128) { sa[t] = a[t]; sb[t] = b[t]; }
    __syncthreads();
    const int row  = (int)((blockIdx.x * 256u + t) >> 6);
    const int lane = t & 63;
    if (row >= N) return;
    const size_t base = (size_t)row * 128;
    float v0 = fmaf(sa[lane],      Y2[base + lane],      sb[lane]);
    float v1 = fmaf(sa[lane + 64], Y2[base + lane + 64], sb[lane + 64]);
    float ss = fmaf(v0, v0, v1 * v1);
#pragma unroll
    for (int o = 32; o; o >>= 1) ss += __shfl_xor(ss, o, 64);
    float nrm = sqrtf(ss);
    float inv = (nrm == 0.f) ? 1.f : 1.f / nrm;
    out[base + lane]      = v0 * inv;
    out[base + lane + 64] = v1 * inv;
}

// ---------------------------------------------------------------------------
extern "C" void kernel_launch(void* const* d_in, const int* in_sizes, int n_in,
                              void* d_out, int out_size, void* d_ws, size_t ws_size,
                              hipStream_t stream)
{
    const float* feat   = (const float*)d_in[0];
    const float* w      = (const float*)d_in[1];
    const float* Q_w    = (const float*)d_in[2];
    const float* Q_b    = (const float*)d_in[3];
    const float* W_w    = (const float*)d_in[4];
    const float* W_b    = (const float*)d_in[5];
    const float* gamma2 = (const float*)d_in[6];
    const float* beta2  = (const float*)d_in[7];
    const int*   src    = (const int*)d_in[8];
    const int*   dst    = (const int*)d_in[9];

    const int N = in_sizes[0] / 128;   // 50000
    const int E = in_sizes[1];         // 800000

    // workspace layout
    float*          y1    = (float*)d_ws;                            // N*128 f32 (y1 then y2)
    unsigned short* featb = (unsigned short*)(y1 + (size_t)N * 128); // N*128 bf16
    unsigned short* aggb  = featb + (size_t)N * 128;                 // N*128 bf16
    unsigned short* h_bf  = aggb + (size_t)N * 128;                  // N*128 bf16
    int4*  tmp    = (int4*)(h_bf + (size_t)N * 128);                 // E (16B aligned)
    int2*  epack  = (int2*)(tmp + E);                                // E
    int*   offs   = (int*)(epack + E);                               // N+1
    int*   coffs  = offs + (N + 1);                                  // 129
    int*   gcur   = coffs + 129;                                     // 128
    float* coefs  = (float*)(gcur + 128);                            // 512
    float* a1 = coefs, *b1 = coefs + 128, *a2 = coefs + 256, *b2 = coefs + 384;
    uintptr_t sp  = ((uintptr_t)(coefs + 512) + 7) & ~(uintptr_t)7;
    double* stats = (double*)sp;                                     // 4*NSLOT*128 <- zeroed
    double* sum1   = stats;
    double* sumsq1 = stats + NSLOT * 128;
    double* sum2   = stats + 2 * NSLOT * 128;
    double* sumsq2 = stats + 3 * NSLOT * 128;
    int*   ccnt   = (int*)(stats + 4 * NSLOT * 128);                 // 128 <- zeroed

    // zero stats + ccnt (contiguous, ~132 KB)
    hipMemsetAsync(stats, 0,
                   4 * NSLOT * 128 * sizeof(double) + 128 * sizeof(int),
                   stream);

    const double invN = 1.0 / (double)N;
    const int gemm_blocks = (N + 63) / 64;
    const int NB = (N + 511) >> 9;              // coarse buckets (98)
    const int CB = (N * 128 / 4 + 255) / 256;   // cast blocks in k_pre
    const int HB = (E + 2047) / 2048;           // histogram blocks in k_pre

    k_pre<<<CB + HB, 256, 0, stream>>>(feat, featb, N * 128, dst, ccnt, E, CB);
    k_coffs<<<1, 128, 0, stream>>>(ccnt, coffs, gcur, offs, N, E);

    k_bin<<<HB, 256, 0, stream>>>(src, dst, w, gcur, tmp, E);
    k_refine<<<NB, 256, 0, stream>>>(tmp, coffs, offs, epack, N);

    gemm_bn<128><<<gemm_blocks, 256, 0, stream>>>(
        featb, featb, Q_w, Q_b, y1, sum1, sumsq1, N);
    bn_coef<<<1, 128, 0, stream>>>(sum1, sumsq1, gamma2, beta2, a1, b1, invN);
    apply_bn_bf16<<<(N * 128 + 1023) / 1024, 256, 0, stream>>>(
        y1, a1, b1, h_bf, N * 128);

    gather_agg<<<(N * 64 + 255) / 256, 256, 0, stream>>>(h_bf, offs, epack, aggb, N);

    gemm_bn<256><<<gemm_blocks, 256, 0, stream>>>(
        featb, aggb, W_w, W_b, y1 /*=y2*/, sum2, sumsq2, N);
    bn_coef<<<1, 128, 0, stream>>>(sum2, sumsq2, gamma2, beta2, a2, b2, invN);
    finalize<<<(N * 64 + 255) / 256, 256, 0, stream>>>(
        y1, a2, b2, (float*)d_out, N);
}

// Round 10
// 245.253 us; speedup vs baseline: 1.3097x; 1.0369x over previous
//
#include <hip/hip_runtime.h>
#include <stdint.h>

// PinConv pipeline: bf16-MFMA GEMMs (fused colstats, striped fp64 atomics) +
// locality-binned CSR gather. Round 10: grid-split FAT kernels merge
// independent chains to cut dispatch count 11->9 and overlap irregular
// (latency-bound) work with MFMA work:
//   fatB = k_bin || gemm1,  fatC = k_refine || apply_bn.

#define BN_EPS 1e-5f
#define NSLOT 32

typedef __attribute__((ext_vector_type(8))) short bf16x8;
typedef __attribute__((ext_vector_type(4))) float f32x4;

static __device__ __forceinline__ unsigned short f2bf(float f) {
    uint32_t u = __builtin_bit_cast(uint32_t, f);
    u += 0x7fffu + ((u >> 16) & 1u);          // round-to-nearest-even
    return (unsigned short)(u >> 16);
}
static __device__ __forceinline__ float bf_lo(uint32_t u) {
    return __builtin_bit_cast(float, u << 16);
}
static __device__ __forceinline__ float bf_hi(uint32_t u) {
    return __builtin_bit_cast(float, u & 0xffff0000u);
}

// ---------------------------------------------------------------------------
// Fused: blocks [0,CB) cast feat f32->bf16; blocks [CB,..) coarse-histogram
// dst into 512-wide buckets (LDS-aggregated, <=98 global atomics per block).
__global__ __launch_bounds__(256) void k_pre(
    const float* __restrict__ feat, unsigned short* __restrict__ featb, int nf,
    const int* __restrict__ dst, int* __restrict__ ccnt, int E, int CB)
{
    if ((int)blockIdx.x < CB) {
        int i = (blockIdx.x * 256 + threadIdx.x) * 4;
        if (i + 3 < nf) {
            float4 v = *(const float4*)(feat + i);
            ushort4 o;
            o.x = f2bf(v.x); o.y = f2bf(v.y); o.z = f2bf(v.z); o.w = f2bf(v.w);
            *(ushort4*)(featb + i) = o;
        } else {
            for (int j = i; j < nf; ++j) featb[j] = f2bf(feat[j]);
        }
    } else {
        __shared__ int hcnt[128];
        const int tid = threadIdx.x;
        if (tid < 128) hcnt[tid] = 0;
        __syncthreads();
        const int base_e = (blockIdx.x - CB) * 2048;
#pragma unroll
        for (int j = 0; j < 8; ++j) {
            int e = base_e + j * 256 + tid;
            if (e < E) atomicAdd(&hcnt[dst[e] >> 9], 1);
        }
        __syncthreads();
        if (tid < 128 && hcnt[tid] > 0) atomicAdd(&ccnt[tid], hcnt[tid]);
    }
}

// ---------------------------------------------------------------------------
// Single block: exclusive scan of 128 bucket counts -> coffs[129], gcur,
// and offs[N] = E.
__global__ __launch_bounds__(128) void k_coffs(
    const int* __restrict__ ccnt, int* __restrict__ coffs,
    int* __restrict__ gcur, int* __restrict__ offs, int N, int E)
{
    __shared__ int w0sum;
    const int t = threadIdx.x;
    const int lane = t & 63, wv = t >> 6;
    int v = ccnt[t];
    int incl = v;
#pragma unroll
    for (int o = 1; o < 64; o <<= 1) {
        int u = __shfl_up(incl, o, 64);
        if (lane >= o) incl += u;
    }
    if (wv == 0 && lane == 63) w0sum = incl;
    __syncthreads();
    int excl = incl - v + (wv ? w0sum : 0);
    coffs[t] = excl;
    gcur[t]  = excl;
    if (t == 127) { coffs[128] = excl + v; offs[N] = E; }
}

// ---------------------------------------------------------------------------
// GEMM body: Y = relu(A @ B^T + bias); A rows from A_lo/A_hi, bf16. B f32,
// converted during staging. Col sum/sumsq -> striped fp64 slots.
template<int K>
static __device__ __forceinline__ void gemm_body(
    int bid,
    const unsigned short* __restrict__ A_lo,
    const unsigned short* __restrict__ A_hi,
    const float* __restrict__ B,
    const float* __restrict__ bias,
    float* __restrict__ Y,
    double* __restrict__ sum, double* __restrict__ sumsq, int N)
{
    constexpr int SA = 72;
    __shared__ unsigned short As[64 * SA];
    __shared__ unsigned short Bs[128 * SA];
    __shared__ float bsum_s[128], bsq_s[128];

    const int tid  = threadIdx.x;
    const int lane = tid & 63;
    const int wv   = tid >> 6;
    const int wr   = wv >> 1;
    const int wc   = wv & 1;
    const int m15  = lane & 15;
    const int quad = lane >> 4;
    const int r0   = bid * 64;

    if (tid < 128) { bsum_s[tid] = 0.f; bsq_s[tid] = 0.f; }

    f32x4 acc[2][4];
#pragma unroll
    for (int rt = 0; rt < 2; ++rt)
#pragma unroll
        for (int ct = 0; ct < 4; ++ct)
            acc[rt][ct] = (f32x4){0.f, 0.f, 0.f, 0.f};

    for (int kc = 0; kc < K; kc += 64) {
        const unsigned short* Ap = (kc < 128) ? A_lo : A_hi;
        const int koff = kc & 127;
#pragma unroll
        for (int i = 0; i < 2; ++i) {
            int idx = i * 256 + tid;
            int row = idx >> 3, seg = idx & 7;
            int gr  = r0 + row; if (gr >= N) gr = N - 1;
            uint4 v = *(const uint4*)(Ap + (size_t)gr * 128 + koff + seg * 8);
            *(uint4*)(As + row * SA + seg * 8) = v;
        }
#pragma unroll
        for (int i = 0; i < 8; ++i) {
            int idx = i * 256 + tid;
            int row = idx >> 4, seg = idx & 15;
            float4 v = *(const float4*)(B + (size_t)row * K + kc + seg * 4);
            ushort4 o;
            o.x = f2bf(v.x); o.y = f2bf(v.y); o.z = f2bf(v.z); o.w = f2bf(v.w);
            *(ushort4*)(Bs + row * SA + seg * 4) = o;
        }
        __syncthreads();

#pragma unroll
        for (int ks = 0; ks < 64; ks += 32) {
            bf16x8 af[2], bfr[4];
#pragma unroll
            for (int rt = 0; rt < 2; ++rt)
                af[rt] = *(const bf16x8*)(As + (wr * 32 + rt * 16 + m15) * SA + ks + quad * 8);
#pragma unroll
            for (int ct = 0; ct < 4; ++ct)
                bfr[ct] = *(const bf16x8*)(Bs + (wc * 64 + ct * 16 + m15) * SA + ks + quad * 8);
#pragma unroll
            for (int rt = 0; rt < 2; ++rt)
#pragma unroll
                for (int ct = 0; ct < 4; ++ct)
                    acc[rt][ct] = __builtin_amdgcn_mfma_f32_16x16x32_bf16(
                        af[rt], bfr[ct], acc[rt][ct], 0, 0, 0);
        }
        __syncthreads();
    }

#pragma unroll
    for (int ct = 0; ct < 4; ++ct) {
        int col = wc * 64 + ct * 16 + m15;
        float bz = bias[col];
        float s = 0.f, q = 0.f;
#pragma unroll
        for (int rt = 0; rt < 2; ++rt) {
#pragma unroll
            for (int reg = 0; reg < 4; ++reg) {
                int row = r0 + wr * 32 + rt * 16 + quad * 4 + reg;
                float v = fmaxf(acc[rt][ct][reg] + bz, 0.f);
                if (row < N) {
                    Y[(size_t)row * 128 + col] = v;
                } else {
                    v = 0.f;
                }
                s += v; q = fmaf(v, v, q);
            }
        }
        s += __shfl_xor(s, 16, 64); s += __shfl_xor(s, 32, 64);
        q += __shfl_xor(q, 16, 64); q += __shfl_xor(q, 32, 64);
        if (quad == 0) {
            atomicAdd(&bsum_s[col], s);
            atomicAdd(&bsq_s[col], q);
        }
    }
    __syncthreads();
    if (tid < 128) {
        const int slot = (bid & (NSLOT - 1)) * 128;
        atomicAdd(&sum[slot + tid],   (double)bsum_s[tid]);
        atomicAdd(&sumsq[slot + tid], (double)bsq_s[tid]);
    }
}

// ---------------------------------------------------------------------------
// bin body: bin edges into coarse buckets of 512 dsts (int4 records).
static __device__ __forceinline__ void bin_body(
    int bid,
    const int* __restrict__ src, const int* __restrict__ dst,
    const float* __restrict__ w, int* __restrict__ gcur,
    int4* __restrict__ tmp, int E)
{
    __shared__ int hcnt[128];
    __shared__ int hbase[128];
    const int tid = threadIdx.x;
    if (tid < 128) hcnt[tid] = 0;
    __syncthreads();

    int d8[8], s8[8], slot8[8];
    float w8[8];
#pragma unroll
    for (int j = 0; j < 8; ++j) {
        int e = bid * 2048 + j * 256 + tid;
        if (e < E) {
            d8[j] = dst[e]; s8[j] = src[e]; w8[j] = w[e];
            slot8[j] = atomicAdd(&hcnt[d8[j] >> 9], 1);
        } else d8[j] = -1;
    }
    __syncthreads();
    if (tid < 128 && hcnt[tid] > 0)
        hbase[tid] = atomicAdd(&gcur[tid], hcnt[tid]);
    __syncthreads();
#pragma unroll
    for (int j = 0; j < 8; ++j) {
        if (d8[j] >= 0) {
            int pos = hbase[d8[j] >> 9] + slot8[j];
            tmp[pos] = make_int4(s8[j], __float_as_int(w8[j]), d8[j], 0);
        }
    }
}

// fatB: blocks [0,HB) bin edges; blocks [HB,HB+GB) run gemm1.
__global__ __launch_bounds__(256) void k_bin_gemm(
    const int* __restrict__ src, const int* __restrict__ dst,
    const float* __restrict__ w, int* __restrict__ gcur,
    int4* __restrict__ tmp, int E, int HB,
    const unsigned short* __restrict__ featb,
    const float* __restrict__ Qw, const float* __restrict__ Qb,
    float* __restrict__ y1,
    double* __restrict__ sum, double* __restrict__ sumsq, int N)
{
    if ((int)blockIdx.x < HB)
        bin_body(blockIdx.x, src, dst, w, gcur, tmp, E);
    else
        gemm_body<128>(blockIdx.x - HB, featb, featb, Qw, Qb, y1, sum, sumsq, N);
}

// ---------------------------------------------------------------------------
// Single block: reduce 32 slots -> bn affine coefs a[128], b[128].
__global__ __launch_bounds__(128) void bn_coef(
    const double* __restrict__ sum, const double* __restrict__ sumsq,
    const float* __restrict__ gamma, const float* __restrict__ beta,
    float* __restrict__ a, float* __restrict__ b, double invN)
{
    const int t = threadIdx.x;  // 128
    double ms = 0.0, qs = 0.0;
#pragma unroll
    for (int s = 0; s < NSLOT; ++s) {
        ms += sum[s * 128 + t];
        qs += sumsq[s * 128 + t];
    }
    float mean = (float)(ms * invN);
    float var  = (float)(qs * invN) - mean * mean;
    float sc = rsqrtf(var + BN_EPS) * gamma[t];
    a[t] = sc;
    b[t] = fmaf(-mean, sc, beta[t]);
}

// ---------------------------------------------------------------------------
// refine body: per bucket — count per-dst in LDS, scan (+coffs base), write
// offs slice, scatter records to epack in exact dst order.
static __device__ __forceinline__ void refine_body(
    int b,
    const int4* __restrict__ tmp, const int* __restrict__ coffs,
    int* __restrict__ offs, int2* __restrict__ epack, int N)
{
    __shared__ int hist[512];
    __shared__ int wpre[4];
    const int d0   = b << 9;
    const int dlim = min(512, N - d0);
    const int tid  = threadIdx.x;
    const int lane = tid & 63, wv = tid >> 6;
    const int start = coffs[b];
    const int end   = coffs[b + 1];

    hist[tid] = 0; hist[tid + 256] = 0;
    __syncthreads();

    for (int p = start + tid; p < end; p += 256)
        atomicAdd(&hist[tmp[p].z - d0], 1);
    __syncthreads();

    int v0 = hist[2 * tid], v1 = hist[2 * tid + 1];
    int s = v0 + v1;
    int incl = s;
#pragma unroll
    for (int o = 1; o < 64; o <<= 1) {
        int t = __shfl_up(incl, o, 64);
        if (lane >= o) incl += t;
    }
    if (lane == 63) wpre[wv] = incl;
    __syncthreads();
    if (tid == 0) {
        int r = 0;
#pragma unroll
        for (int i = 0; i < 4; ++i) { int t = wpre[i]; wpre[i] = r; r += t; }
    }
    __syncthreads();
    int e0 = start + wpre[wv] + incl - s;
    if (2 * tid < dlim)     offs[d0 + 2 * tid]     = e0;
    if (2 * tid + 1 < dlim) offs[d0 + 2 * tid + 1] = e0 + v0;
    hist[2 * tid]     = e0;
    hist[2 * tid + 1] = e0 + v0;
    __syncthreads();

    for (int p = start + tid; p < end; p += 256) {
        int4 rec = tmp[p];
        int pos = atomicAdd(&hist[rec.z - d0], 1);
        epack[pos] = make_int2(rec.x, rec.y);
    }
}

// fatC: blocks [0,NB) refine buckets; blocks [NB,..) apply bn -> h bf16.
__global__ __launch_bounds__(256) void k_refine_apply(
    const int4* __restrict__ tmp, const int* __restrict__ coffs,
    int* __restrict__ offs, int2* __restrict__ epack, int N, int NB,
    const float* __restrict__ y,
    const float* __restrict__ a, const float* __restrict__ b,
    unsigned short* __restrict__ h, int n)
{
    if ((int)blockIdx.x < NB) {
        refine_body(blockIdx.x, tmp, coffs, offs, epack, N);
    } else {
        int i = ((blockIdx.x - NB) * 256 + threadIdx.x) * 4;
        if (i >= n) return;
        int c = i & 127;
        float4 v  = *(const float4*)(y + i);
        float4 av = *(const float4*)(a + c);
        float4 bv = *(const float4*)(b + c);
        ushort4 o;
        o.x = f2bf(fmaf(av.x, v.x, bv.x));
        o.y = f2bf(fmaf(av.y, v.y, bv.y));
        o.z = f2bf(fmaf(av.z, v.z, bv.z));
        o.w = f2bf(fmaf(av.w, v.w, bv.w));
        *(ushort4*)(h + i) = o;
    }
}

// ---------------------------------------------------------------------------
// One wave per dst row; h bf16 (bn applied). Writes agg only (bf16).
__global__ __launch_bounds__(256) void gather_agg(
    const unsigned short* __restrict__ h,
    const int* __restrict__ offs, const int2* __restrict__ epack,
    unsigned short* __restrict__ aggb, int N)
{
    const int r    = (int)((blockIdx.x * 256u + threadIdx.x) >> 6);
    const int lane = threadIdx.x & 63;
    if (r >= N) return;
    int p = offs[r];
    const int end = offs[r + 1];
    float nx = 0.f, ny = 0.f, den = 0.f;
    for (; p + 3 < end; p += 4) {
        int2 e0 = epack[p],     e1 = epack[p + 1];
        int2 e2 = epack[p + 2], e3 = epack[p + 3];
        uint32_t u0 = *(const uint32_t*)(h + (size_t)e0.x * 128 + 2 * lane);
        uint32_t u1 = *(const uint32_t*)(h + (size_t)e1.x * 128 + 2 * lane);
        uint32_t u2 = *(const uint32_t*)(h + (size_t)e2.x * 128 + 2 * lane);
        uint32_t u3 = *(const uint32_t*)(h + (size_t)e3.x * 128 + 2 * lane);
        float w0 = __int_as_float(e0.y), w1 = __int_as_float(e1.y);
        float w2 = __int_as_float(e2.y), w3 = __int_as_float(e3.y);
        nx = fmaf(w0, bf_lo(u0), nx); ny = fmaf(w0, bf_hi(u0), ny);
        nx = fmaf(w1, bf_lo(u1), nx); ny = fmaf(w1, bf_hi(u1), ny);
        nx = fmaf(w2, bf_lo(u2), nx); ny = fmaf(w2, bf_hi(u2), ny);
        nx = fmaf(w3, bf_lo(u3), nx); ny = fmaf(w3, bf_hi(u3), ny);
        den += (w0 + w1) + (w2 + w3);
    }
    for (; p < end; ++p) {
        int2 e0 = epack[p];
        float w0 = __int_as_float(e0.y);
        uint32_t u0 = *(const uint32_t*)(h + (size_t)e0.x * 128 + 2 * lane);
        nx = fmaf(w0, bf_lo(u0), nx); ny = fmaf(w0, bf_hi(u0), ny);
        den += w0;
    }
    float2 outv;
    if (den != 0.f) {
        float inv = 1.f / den;
        outv.x = nx * inv; outv.y = ny * inv;
    } else {
        uint32_t u = *(const uint32_t*)(h + (size_t)r * 128 + 2 * lane);
        outv.x = bf_lo(u); outv.y = bf_hi(u);
    }
    ushort2 ao; ao.x = f2bf(outv.x); ao.y = f2bf(outv.y);
    *(ushort2*)&aggb[(size_t)r * 128 + 2 * lane] = ao;
}

// ---------------------------------------------------------------------------
// gemm2 standalone (K=256, A = [featb|aggb]).
__global__ __launch_bounds__(256) void gemm_bn2(
    const unsigned short* __restrict__ A_lo,
    const unsigned short* __restrict__ A_hi,
    const float* __restrict__ B,
    const float* __restrict__ bias,
    float* __restrict__ Y,
    double* __restrict__ sum, double* __restrict__ sumsq, int N)
{
    gemm_body<256>(blockIdx.x, A_lo, A_hi, B, bias, Y, sum, sumsq, N);
}

// ---------------------------------------------------------------------------
// bn2 affine (precomputed coefs) + row L2 normalize.
__global__ __launch_bounds__(256) void finalize(
    const float* __restrict__ Y2,
    const float* __restrict__ a, const float* __restrict__ b,
    float* __restrict__ out, int N)
{
    __shared__ float sa[128], sb[128];
    const int t = threadIdx.x;
    if (t < 128) { sa[t] = a[t]; sb[t] = b[t]; }
    __syncthreads();
    const int row  = (int)((blockIdx.x * 256u + t) >> 6);
    const int lane = t & 63;
    if (row >= N) return;
    const size_t base = (size_t)row * 128;
    float v0 = fmaf(sa[lane],      Y2[base + lane],      sb[lane]);
    float v1 = fmaf(sa[lane + 64], Y2[base + lane + 64], sb[lane + 64]);
    float ss = fmaf(v0, v0, v1 * v1);
#pragma unroll
    for (int o = 32; o; o >>= 1) ss += __shfl_xor(ss, o, 64);
    float nrm = sqrtf(ss);
    float inv = (nrm == 0.f) ? 1.f : 1.f / nrm;
    out[base + lane]      = v0 * inv;
    out[base + lane + 64] = v1 * inv;
}

// ---------------------------------------------------------------------------
extern "C" void kernel_launch(void* const* d_in, const int* in_sizes, int n_in,
                              void* d_out, int out_size, void* d_ws, size_t ws_size,
                              hipStream_t stream)
{
    const float* feat   = (const float*)d_in[0];
    const float* w      = (const float*)d_in[1];
    const float* Q_w    = (const float*)d_in[2];
    const float* Q_b    = (const float*)d_in[3];
    const float* W_w    = (const float*)d_in[4];
    const float* W_b    = (const float*)d_in[5];
    const float* gamma2 = (const float*)d_in[6];
    const float* beta2  = (const float*)d_in[7];
    const int*   src    = (const int*)d_in[8];
    const int*   dst    = (const int*)d_in[9];

    const int N = in_sizes[0] / 128;   // 50000
    const int E = in_sizes[1];         // 800000

    // workspace layout
    float*          y1    = (float*)d_ws;                            // N*128 f32 (y1 then y2)
    unsigned short* featb = (unsigned short*)(y1 + (size_t)N * 128); // N*128 bf16
    unsigned short* aggb  = featb + (size_t)N * 128;                 // N*128 bf16
    unsigned short* h_bf  = aggb + (size_t)N * 128;                  // N*128 bf16
    int4*  tmp    = (int4*)(h_bf + (size_t)N * 128);                 // E (16B aligned)
    int2*  epack  = (int2*)(tmp + E);                                // E
    int*   offs   = (int*)(epack + E);                               // N+1
    int*   coffs  = offs + (N + 1);                                  // 129
    int*   gcur   = coffs + 129;                                     // 128
    float* coefs  = (float*)(gcur + 128);                            // 512
    float* a1 = coefs, *b1 = coefs + 128, *a2 = coefs + 256, *b2 = coefs + 384;
    uintptr_t sp  = ((uintptr_t)(coefs + 512) + 7) & ~(uintptr_t)7;
    double* stats = (double*)sp;                                     // 4*NSLOT*128 <- zeroed
    double* sum1   = stats;
    double* sumsq1 = stats + NSLOT * 128;
    double* sum2   = stats + 2 * NSLOT * 128;
    double* sumsq2 = stats + 3 * NSLOT * 128;
    int*   ccnt   = (int*)(stats + 4 * NSLOT * 128);                 // 128 <- zeroed

    hipMemsetAsync(stats, 0,
                   4 * NSLOT * 128 * sizeof(double) + 128 * sizeof(int),
                   stream);

    const double invN = 1.0 / (double)N;
    const int GB = (N + 63) / 64;               // gemm blocks (782)
    const int NB = (N + 511) >> 9;              // coarse buckets (98)
    const int CB = (N * 128 / 4 + 255) / 256;   // cast blocks in k_pre
    const int HB = (E + 2047) / 2048;           // histogram/bin blocks
    const int AB = (N * 128 / 4 + 255) / 256;   // apply_bn blocks

    k_pre<<<CB + HB, 256, 0, stream>>>(feat, featb, N * 128, dst, ccnt, E, CB);
    k_coffs<<<1, 128, 0, stream>>>(ccnt, coffs, gcur, offs, N, E);

    // fatB: bin || gemm1
    k_bin_gemm<<<HB + GB, 256, 0, stream>>>(
        src, dst, w, gcur, tmp, E, HB,
        featb, Q_w, Q_b, y1, sum1, sumsq1, N);
    bn_coef<<<1, 128, 0, stream>>>(sum1, sumsq1, gamma2, beta2, a1, b1, invN);

    // fatC: refine || apply_bn
    k_refine_apply<<<NB + AB, 256, 0, stream>>>(
        tmp, coffs, offs, epack, N, NB,
        y1, a1, b1, h_bf, N * 128);

    gather_agg<<<(N * 64 + 255) / 256, 256, 0, stream>>>(h_bf, offs, epack, aggb, N);

    gemm_bn2<<<GB, 256, 0, stream>>>(
        featb, aggb, W_w, W_b, y1 /*=y2*/, sum2, sumsq2, N);
    bn_coef<<<1, 128, 0, stream>>>(sum2, sumsq2, gamma2, beta2, a2, b2, invN);
    finalize<<<(N * 64 + 255) / 256, 256, 0, stream>>>(
        y1, a2, b2, (float*)d_out, N);
}